// Round 3
// baseline (35628.711 us; speedup 1.0000x reference)
//
#include <hip/hip_runtime.h>
#include <math.h>

// Problem constants
#define Bsz   256
#define Hd    512
#define Din   512
#define Lenc  48
#define Look  10
#define G4    2048     // 4*H
#define LabStride 58   // LENC + LDEC
#define StartIdx  48   // LDEC + LENC - LOOK

typedef unsigned short u16;
using bfrag = __attribute__((ext_vector_type(8))) short;   // 8 bf16 (4 VGPRs)
using f32x4 = __attribute__((ext_vector_type(4))) float;   // 4 fp32 acc

#define MFMA16(a,b,c) __builtin_amdgcn_mfma_f32_16x16x32_bf16((a),(b),(c),0,0,0)

__device__ __forceinline__ u16 f2bf(float f){
  unsigned u = __float_as_uint(f);
  u += 0x7FFFu + ((u>>16)&1u);               // RNE
  return (u16)(u>>16);
}
__device__ __forceinline__ float bf2f(u16 h){ return __uint_as_float(((unsigned)h)<<16); }
__device__ __forceinline__ float sigm(float x){ return 1.f/(1.f+__expf(-x)); }

// ---- 32x32 output tile per wave, K-loop of 16x16x32 MFMAs ----
// A: activations [m][k] row-major (lda), W: weights [n][k] row-major (ldw) == B^T.
// Frag layout (m89/m91): A row = lane&15, k = 8*(lane>>4)+j ; same for W (row->n).
// acc[4] = [mi*2+ni], D: col(n)=lane&15, row(m)=4*(lane>>4)+reg.
template<int K>
__device__ __forceinline__ void mm32(const u16* __restrict__ A, int lda,
                                     const u16* __restrict__ W, int ldw,
                                     f32x4* acc, int lane){
  const int rr = lane & 15, ko = (lane>>4)<<3;
  const u16* a0 = A + (size_t)rr*lda + ko;
  const u16* a1 = a0 + 16*(size_t)lda;
  const u16* w0 = W + (size_t)rr*ldw + ko;
  const u16* w1 = w0 + 16*(size_t)ldw;
#pragma unroll
  for(int k=0;k<K;k+=32){
    bfrag av0 = *(const bfrag*)(a0+k);
    bfrag av1 = *(const bfrag*)(a1+k);
    bfrag wv0 = *(const bfrag*)(w0+k);
    bfrag wv1 = *(const bfrag*)(w1+k);
    acc[0] = MFMA16(av0,wv0,acc[0]);
    acc[1] = MFMA16(av0,wv1,acc[1]);
    acc[2] = MFMA16(av1,wv0,acc[2]);
    acc[3] = MFMA16(av1,wv1,acc[3]);
  }
}

// ---------------- setup kernels ----------------
__global__ void k_cvt(const float* __restrict__ s, u16* __restrict__ d, int n){
  for(int i=blockIdx.x*blockDim.x+threadIdx.x; i<n; i+=gridDim.x*blockDim.x) d[i]=f2bf(s[i]);
}

// Wih_tg is (2048 x 513): col0 -> c0 (fp32), cols 1..512 -> packed bf16
__global__ void k_cvt_tg(const float* __restrict__ s, u16* __restrict__ d, float* __restrict__ c0){
  int stride=gridDim.x*blockDim.x;
  for(int i=blockIdx.x*blockDim.x+threadIdx.x; i<G4*Hd; i+=stride){
    int n=i>>9, k=i&511;
    d[i]=f2bf(s[n*513+1+k]);
  }
  for(int n=blockIdx.x*blockDim.x+threadIdx.x; n<G4; n+=stride) c0[n]=s[n*513];
}

__global__ void k_init(const float* __restrict__ label, float* __restrict__ lab){
  int b=threadIdx.x;
  if(b<Bsz) lab[b]=label[b*LabStride+StartIdx];
}

// wi_seq[l][b][h] = input[b][l][:] . Wi_w[h][:] + Wi_b[h]   (M=B*Lenc rows (b,l))
__global__ __launch_bounds__(64) void k_wi(const u16* __restrict__ inpb, const u16* __restrict__ Wi,
                     const float* __restrict__ Wib, float* __restrict__ wi_seq){
  int lane=threadIdx.x;
  int r0=blockIdx.x*32, h0=blockIdx.y*32;
  f32x4 acc[4]={};
  mm32<Din>(inpb+(size_t)r0*Din, Din, Wi+(size_t)h0*Din, Din, acc, lane);
  int cr=(lane>>4)*4, cc=lane&15;
  for(int mi=0;mi<2;mi++)for(int ni=0;ni<2;ni++){
    int h=h0+ni*16+cc; float bias=Wib[h];
    f32x4 a=acc[mi*2+ni];
    for(int j=0;j<4;j++){
      int g=r0+mi*16+cr+j;
      int b=g/Lenc, l=g-b*Lenc;
      wi_seq[((size_t)l*Bsz+b)*Hd + h] = a[j]+bias;
    }
  }
}

// ---------------- per-step GEMM kernels (2 waves: K-split, LDS reduce) ----------------

// spre = tanh([he,ce] @ We^T + wi_l + wt) -> bf16
__global__ __launch_bounds__(128) void k_spre(const u16* __restrict__ he, const u16* __restrict__ ce,
      const u16* __restrict__ We, const float* __restrict__ wi_l, const float* __restrict__ wt,
      u16* __restrict__ spre, int zhc){
  int lane=threadIdx.x&63, wid=threadIdx.x>>6;
  int b0=blockIdx.x*32, h0=blockIdx.y*32;
  f32x4 acc[4]={};
  if(!zhc){
    if(wid==0) mm32<Hd>(he+(size_t)b0*Hd, Hd, We+(size_t)h0*1024,     1024, acc, lane);
    else       mm32<Hd>(ce+(size_t)b0*Hd, Hd, We+(size_t)h0*1024+512, 1024, acc, lane);
  }
  __shared__ f32x4 red[4*64];
  if(wid==1){ for(int i=0;i<4;i++) red[i*64+lane]=acc[i]; }
  __syncthreads();
  if(wid!=0) return;
  for(int i=0;i<4;i++) acc[i]+=red[i*64+lane];
  int cr=(lane>>4)*4, cc=lane&15;
  for(int mi=0;mi<2;mi++)for(int ni=0;ni<2;ni++){
    int h=h0+ni*16+cc;
    f32x4 a=acc[mi*2+ni];
    for(int j=0;j<4;j++){
      int b=b0+mi*16+cr+j;
      size_t ix=(size_t)b*Hd+h;
      spre[ix]=f2bf(tanhf(a[j]+wi_l[ix]+wt[ix]));
    }
  }
}

// C = A1 @ W[:, :512]^T + A2 @ W[:, 512:]^T   (fp32 out; used for wt and wh)
__global__ __launch_bounds__(128) void k_dual(const u16* __restrict__ A1, const u16* __restrict__ A2,
      const u16* __restrict__ W, float* __restrict__ C){
  int lane=threadIdx.x&63, wid=threadIdx.x>>6;
  int b0=blockIdx.x*32, h0=blockIdx.y*32;
  f32x4 acc[4]={};
  if(wid==0) mm32<Hd>(A1+(size_t)b0*Hd, Hd, W+(size_t)h0*1024,     1024, acc, lane);
  else       mm32<Hd>(A2+(size_t)b0*Hd, Hd, W+(size_t)h0*1024+512, 1024, acc, lane);
  __shared__ f32x4 red[4*64];
  if(wid==1){ for(int i=0;i<4;i++) red[i*64+lane]=acc[i]; }
  __syncthreads();
  if(wid!=0) return;
  for(int i=0;i<4;i++) acc[i]+=red[i*64+lane];
  int cr=(lane>>4)*4, cc=lane&15;
  for(int mi=0;mi<2;mi++)for(int ni=0;ni<2;ni++){
    int h=h0+ni*16+cc;
    f32x4 a=acc[mi*2+ni];
    for(int j=0;j<4;j++){
      int b=b0+mi*16+cr+j;
      C[(size_t)b*Hd+h]=a[j];
    }
  }
}

// score = spre @ Vd^T + Vd_b  (fp32 out; K=512 split across 2 waves)
__global__ __launch_bounds__(128) void k_sgemm(const u16* __restrict__ spre, const u16* __restrict__ Vd,
      const float* __restrict__ Vdb, float* __restrict__ score){
  int lane=threadIdx.x&63, wid=threadIdx.x>>6;
  int b0=blockIdx.x*32, h0=blockIdx.y*32;
  f32x4 acc[4]={};
  mm32<256>(spre+(size_t)b0*Hd + wid*256, Hd, Vd+(size_t)h0*Hd + wid*256, Hd, acc, lane);
  __shared__ f32x4 red[4*64];
  if(wid==1){ for(int i=0;i<4;i++) red[i*64+lane]=acc[i]; }
  __syncthreads();
  if(wid!=0) return;
  for(int i=0;i<4;i++) acc[i]+=red[i*64+lane];
  int cr=(lane>>4)*4, cc=lane&15;
  for(int mi=0;mi<2;mi++)for(int ni=0;ni<2;ni++){
    int h=h0+ni*16+cc; float bias=Vdb[h];
    f32x4 a=acc[mi*2+ni];
    for(int j=0;j<4;j++){
      int b=b0+mi*16+cr+j;
      score[(size_t)b*Hd+h]=a[j]+bias;
    }
  }
}

// row softmax over 512 + x_mod = x_i * p  -> bf16
__global__ __launch_bounds__(256) void k_softmax(const float* __restrict__ score,
      const float* __restrict__ inp, int l, u16* __restrict__ xmod){
  int b=blockIdx.x, tid=threadIdx.x;
  float s0=score[(size_t)b*Din+tid], s1=score[(size_t)b*Din+256+tid];
  float m=fmaxf(s0,s1);
  for(int o=1;o<64;o<<=1) m=fmaxf(m,__shfl_xor(m,o));
  __shared__ float r1[4], r2[4];
  if((tid&63)==0) r1[tid>>6]=m;
  __syncthreads();
  m=fmaxf(fmaxf(r1[0],r1[1]),fmaxf(r1[2],r1[3]));
  float e0=__expf(s0-m), e1=__expf(s1-m);
  float ss=e0+e1;
  for(int o=1;o<64;o<<=1) ss+=__shfl_xor(ss,o);
  if((tid&63)==0) r2[tid>>6]=ss;
  __syncthreads();
  float inv=1.f/(r2[0]+r2[1]+r2[2]+r2[3]);
  const float* xr = inp + ((size_t)b*Lenc+l)*Din;
  xmod[(size_t)b*Din+tid]     = f2bf(xr[tid]*e0*inv);
  xmod[(size_t)b*Din+256+tid] = f2bf(xr[256+tid]*e1*inv);
}

// Fused LSTM gates GEMM + cell. gates = A1@Wih^T + A2@Whh^T + (bih+bhh).
// wave0: x-part, wave1: h-part (skipped if l0 -> h=c=0). Epilogue: cell math.
__global__ __launch_bounds__(128) void k_cell(const u16* __restrict__ A1, const u16* __restrict__ A2,
     const u16* __restrict__ Wih, const u16* __restrict__ Whh,
     const float* __restrict__ bih, const float* __restrict__ bhh,
     float* __restrict__ cst, u16* __restrict__ cbf, u16* __restrict__ hout, int l0){
  int lane=threadIdx.x&63, wid=threadIdx.x>>6;
  int b0=blockIdx.x*32, h0=blockIdx.y*32;
  f32x4 acc[4][4]={};   // [gate][mi*2+ni]
  if(wid==0){
    for(int g=0;g<4;g++) mm32<Hd>(A1+(size_t)b0*Hd, Hd, Wih+((size_t)g*Hd+h0)*Hd, Hd, acc[g], lane);
  } else if(!l0){
    for(int g=0;g<4;g++) mm32<Hd>(A2+(size_t)b0*Hd, Hd, Whh+((size_t)g*Hd+h0)*Hd, Hd, acc[g], lane);
  }
  __shared__ f32x4 red[16*64];
  if(wid==1){ for(int i=0;i<16;i++) red[i*64+lane]=acc[i>>2][i&3]; }
  __syncthreads();
  if(wid!=0) return;
  for(int i=0;i<16;i++) acc[i>>2][i&3]+=red[i*64+lane];
  int cr=(lane>>4)*4, cc=lane&15;
  for(int mi=0;mi<2;mi++)for(int ni=0;ni<2;ni++){
    int h=h0+ni*16+cc; int tq=mi*2+ni;
    float bi =bih[h]+bhh[h];
    float bff=bih[Hd+h]+bhh[Hd+h];
    float bg =bih[2*Hd+h]+bhh[2*Hd+h];
    float bo =bih[3*Hd+h]+bhh[3*Hd+h];
    for(int j=0;j<4;j++){
      int b=b0+mi*16+cr+j;
      size_t ix=(size_t)b*Hd+h;
      float ii=sigm(acc[0][tq][j]+bi);
      float ff=sigm(acc[1][tq][j]+bff);
      float gg=tanhf(acc[2][tq][j]+bg);
      float oo=sigm(acc[3][tq][j]+bo);
      float cold=l0?0.f:cst[ix];
      float c2=ff*cold+ii*gg;
      float hv=oo*tanhf(c2);
      cst[ix]=c2;
      if(cbf) cbf[ix]=f2bf(c2);
      hout[ix]=f2bf(hv);
    }
  }
}

// tg cell: like k_cell but x = [lab, dec_in] (col0 handled via c0 in epilogue)
__global__ __launch_bounds__(128) void k_tg(const u16* __restrict__ dec, const u16* __restrict__ ht,
    const u16* __restrict__ Wih, const u16* __restrict__ Whh,
    const float* __restrict__ c0, const float* __restrict__ bih, const float* __restrict__ bhh,
    const float* __restrict__ lab, float* __restrict__ cst, u16* __restrict__ cbf,
    u16* __restrict__ hout, int t0){
  int lane=threadIdx.x&63, wid=threadIdx.x>>6;
  int b0=blockIdx.x*32, h0=blockIdx.y*32;
  f32x4 acc[4][4]={};
  if(!t0){
    if(wid==0){ for(int g=0;g<4;g++) mm32<Hd>(dec+(size_t)b0*Hd, Hd, Wih+((size_t)g*Hd+h0)*Hd, Hd, acc[g], lane); }
    else      { for(int g=0;g<4;g++) mm32<Hd>(ht +(size_t)b0*Hd, Hd, Whh+((size_t)g*Hd+h0)*Hd, Hd, acc[g], lane); }
  }
  __shared__ f32x4 red[16*64];
  if(wid==1){ for(int i=0;i<16;i++) red[i*64+lane]=acc[i>>2][i&3]; }
  __syncthreads();
  if(wid!=0) return;
  for(int i=0;i<16;i++) acc[i>>2][i&3]+=red[i*64+lane];
  int cr=(lane>>4)*4, cc=lane&15;
  for(int mi=0;mi<2;mi++)for(int ni=0;ni<2;ni++){
    int h=h0+ni*16+cc; int tq=mi*2+ni;
    float bi =bih[h]+bhh[h];
    float bff=bih[Hd+h]+bhh[Hd+h];
    float bg =bih[2*Hd+h]+bhh[2*Hd+h];
    float bo =bih[3*Hd+h]+bhh[3*Hd+h];
    float ci=c0[h], cf=c0[Hd+h], cg=c0[2*Hd+h], co=c0[3*Hd+h];
    for(int j=0;j<4;j++){
      int b=b0+mi*16+cr+j;
      size_t ix=(size_t)b*Hd+h;
      float lb=lab[b];
      float ii=sigm(acc[0][tq][j]+bi +lb*ci);
      float ff=sigm(acc[1][tq][j]+bff+lb*cf);
      float gg=tanhf(acc[2][tq][j]+bg +lb*cg);
      float oo=sigm(acc[3][tq][j]+bo +lb*co);
      float cold=t0?0.f:cst[ix];
      float c2=ff*cold+ii*gg;
      float hv=oo*tanhf(c2);
      cst[ix]=c2; cbf[ix]=f2bf(c2); hout[ix]=f2bf(hv);
    }
  }
}

// target = ht @ reg_w^T + reg_b ; out[b*Look+t] and lab update
__global__ __launch_bounds__(64) void k_target(const u16* __restrict__ ht, const float* __restrict__ regw,
     const float* __restrict__ regb, float* __restrict__ outp, float* __restrict__ lab, int t){
  int b=blockIdx.x, lane=threadIdx.x;
  bfrag v=*(const bfrag*)(ht+(size_t)b*Hd+lane*8);
  const float* w=regw+lane*8;
  float a=0;
  for(int j=0;j<8;j++) a+=bf2f((u16)v[j])*w[j];
  for(int o=1;o<64;o<<=1) a+=__shfl_xor(a,o);
  if(lane==0){ float val=a+regb[0]; outp[b*Look+t]=val; lab[b]=val; }
}

// TT = tanh(mid2 @ Wx^T + wh[b] + Wx_b)  (M = Lenc*B rows)
__global__ __launch_bounds__(128) void k_scgemm(const u16* __restrict__ mid2, const u16* __restrict__ Wx,
      const float* __restrict__ Wxb, const float* __restrict__ wh, u16* __restrict__ TT){
  int lane=threadIdx.x&63, wid=threadIdx.x>>6;
  int r0=blockIdx.x*32, h0=blockIdx.y*32;
  f32x4 acc[4]={};
  mm32<256>(mid2+(size_t)r0*Hd + wid*256, Hd, Wx+(size_t)h0*Hd + wid*256, Hd, acc, lane);
  __shared__ f32x4 red[4*64];
  if(wid==1){ for(int i=0;i<4;i++) red[i*64+lane]=acc[i]; }
  __syncthreads();
  if(wid!=0) return;
  for(int i=0;i<4;i++) acc[i]+=red[i*64+lane];
  int cr=(lane>>4)*4, cc=lane&15;
  for(int mi=0;mi<2;mi++)for(int ni=0;ni<2;ni++){
    int h=h0+ni*16+cc; float wb=Wxb[h];
    f32x4 a=acc[mi*2+ni];
    for(int j=0;j<4;j++){
      int row=r0+mi*16+cr+j;
      int b=row&255;
      TT[(size_t)row*Hd+h]=f2bf(tanhf(a[j]+wh[(size_t)b*Hd+h]+wb));
    }
  }
}

// sc[b][l] = TT[row] . V_w + V_b   (row = l*B + b)
__global__ __launch_bounds__(64) void k_scred(const u16* __restrict__ TT, const float* __restrict__ Vw,
      const float* __restrict__ Vb, float* __restrict__ sc){
  int row=blockIdx.x, lane=threadIdx.x;
  bfrag v=*(const bfrag*)(TT+(size_t)row*Hd+lane*8);
  const float* w=Vw+lane*8;
  float a=0;
  for(int j=0;j<8;j++) a+=bf2f((u16)v[j])*w[j];
  for(int o=1;o<64;o<<=1) a+=__shfl_xor(a,o);
  if(lane==0){ int l=row>>8, b=row&255; sc[b*Lenc+l]=a+Vb[0]; }
}

// dec_in[b][h] = sum_l sc[b][l] * mid2[l][b][h]
__global__ __launch_bounds__(256) void k_dec(const float* __restrict__ sc, const u16* __restrict__ mid2,
      u16* __restrict__ dec){
  __shared__ float s[Lenc];
  int b=blockIdx.x, tid=threadIdx.x;
  if(tid<Lenc) s[tid]=sc[b*Lenc+tid];
  __syncthreads();
  for(int h=tid; h<Hd; h+=256){
    float a=0;
    for(int l=0;l<Lenc;l++) a+=s[l]*bf2f(mid2[((size_t)l*Bsz+b)*Hd+h]);
    dec[(size_t)b*Hd+h]=f2bf(a);
  }
}

// ---------------- host ----------------
extern "C" void kernel_launch(void* const* d_in, const int* in_sizes, int n_in,
                              void* d_out, int out_size, void* d_ws, size_t ws_size,
                              hipStream_t stream){
  const float* f_inp    =(const float*)d_in[0];
  const float* f_label  =(const float*)d_in[1];
  const float* f_Wih_sp =(const float*)d_in[2];
  const float* f_Whh_sp =(const float*)d_in[3];
  const float* f_bih_sp =(const float*)d_in[4];
  const float* f_bhh_sp =(const float*)d_in[5];
  const float* f_Wih_tg =(const float*)d_in[6];
  const float* f_Whh_tg =(const float*)d_in[7];
  const float* f_bih_tg =(const float*)d_in[8];
  const float* f_bhh_tg =(const float*)d_in[9];
  const float* f_Wih_mid=(const float*)d_in[10];
  const float* f_Whh_mid=(const float*)d_in[11];
  const float* f_bih_mid=(const float*)d_in[12];
  const float* f_bhh_mid=(const float*)d_in[13];
  const float* f_Wi_w   =(const float*)d_in[14];
  const float* f_Wi_b   =(const float*)d_in[15];
  const float* f_We_w   =(const float*)d_in[16];
  const float* f_Wt_w   =(const float*)d_in[17];
  const float* f_Vd_w   =(const float*)d_in[18];
  const float* f_Vd_b   =(const float*)d_in[19];
  const float* f_Wx_w   =(const float*)d_in[20];
  const float* f_Wx_b   =(const float*)d_in[21];
  const float* f_Wh_w   =(const float*)d_in[22];
  const float* f_V_w    =(const float*)d_in[23];
  const float* f_V_b    =(const float*)d_in[24];
  const float* f_reg_w  =(const float*)d_in[25];
  const float* f_reg_b  =(const float*)d_in[26];
  float* outp=(float*)d_out;

  char* basep=(char*)d_ws; size_t off=0;
  auto alloc=[&](size_t bytes)->void*{ void* r=basep+off; off+=(bytes+255)&~((size_t)255); return r; };

  const size_t BH=(size_t)Bsz*Hd;
  u16*  wspih =(u16*)alloc((size_t)G4*Hd*2);
  u16*  wsphh =(u16*)alloc((size_t)G4*Hd*2);
  u16*  wtgih =(u16*)alloc((size_t)G4*Hd*2);
  u16*  wtghh =(u16*)alloc((size_t)G4*Hd*2);
  u16*  wmidih=(u16*)alloc((size_t)G4*Hd*2);
  u16*  wmidhh=(u16*)alloc((size_t)G4*Hd*2);
  u16*  web   =(u16*)alloc((size_t)Hd*1024*2);
  u16*  wtb   =(u16*)alloc((size_t)Hd*1024*2);
  u16*  whb   =(u16*)alloc((size_t)Hd*1024*2);
  u16*  vdb   =(u16*)alloc((size_t)Hd*Hd*2);
  u16*  wxb   =(u16*)alloc((size_t)Hd*Hd*2);
  u16*  wib   =(u16*)alloc((size_t)Hd*Hd*2);
  u16*  inpb  =(u16*)alloc((size_t)Bsz*Lenc*Din*2);
  float* c0f  =(float*)alloc((size_t)G4*4);
  float* wiseq=(float*)alloc((size_t)Lenc*BH*4);
  u16*  midb  =(u16*)alloc((size_t)Lenc*BH*2);
  u16*  mid2b =(u16*)alloc((size_t)Lenc*BH*2);
  u16*  ttb   =(u16*)alloc((size_t)Lenc*BH*2);
  u16*  spreb =(u16*)alloc(BH*2);
  float* scoref=(float*)alloc(BH*4);
  u16*  xmodb =(u16*)alloc(BH*2);
  float* cef  =(float*)alloc(BH*4);
  u16*  ceb   =(u16*)alloc(BH*2);
  float* ctf  =(float*)alloc(BH*4);
  u16*  ctb   =(u16*)alloc(BH*2);
  float* cmidf=(float*)alloc(BH*4);
  u16*  ht0   =(u16*)alloc(BH*2);
  u16*  ht1   =(u16*)alloc(BH*2);
  u16*  decb  =(u16*)alloc(BH*2);
  float* wtf  =(float*)alloc(BH*4);
  float* whf  =(float*)alloc(BH*4);
  float* labf =(float*)alloc((size_t)Bsz*4);
  float* scf  =(float*)alloc((size_t)Bsz*Lenc*4);

  dim3 cvtg(512), cvtb(256);
  k_cvt<<<cvtg,cvtb,0,stream>>>(f_Wih_sp ,wspih ,G4*Hd);
  k_cvt<<<cvtg,cvtb,0,stream>>>(f_Whh_sp ,wsphh ,G4*Hd);
  k_cvt<<<cvtg,cvtb,0,stream>>>(f_Whh_tg ,wtghh ,G4*Hd);
  k_cvt<<<cvtg,cvtb,0,stream>>>(f_Wih_mid,wmidih,G4*Hd);
  k_cvt<<<cvtg,cvtb,0,stream>>>(f_Whh_mid,wmidhh,G4*Hd);
  k_cvt<<<cvtg,cvtb,0,stream>>>(f_We_w   ,web   ,Hd*1024);
  k_cvt<<<cvtg,cvtb,0,stream>>>(f_Wt_w   ,wtb   ,Hd*1024);
  k_cvt<<<cvtg,cvtb,0,stream>>>(f_Wh_w   ,whb   ,Hd*1024);
  k_cvt<<<cvtg,cvtb,0,stream>>>(f_Vd_w   ,vdb   ,Hd*Hd);
  k_cvt<<<cvtg,cvtb,0,stream>>>(f_Wx_w   ,wxb   ,Hd*Hd);
  k_cvt<<<cvtg,cvtb,0,stream>>>(f_Wi_w   ,wib   ,Hd*Hd);
  k_cvt<<<dim3(1024),cvtb,0,stream>>>(f_inp, inpb, Bsz*Lenc*Din);
  k_cvt_tg<<<cvtg,cvtb,0,stream>>>(f_Wih_tg, wtgih, c0f);
  k_init<<<dim3(1),dim3(256),0,stream>>>(f_label, labf);
  k_wi<<<dim3(384,16),dim3(64),0,stream>>>(inpb, wib, f_Wi_b, wiseq);

  dim3 g816(8,16), b128(128);
  u16 *htR=ht0, *htW=ht1;
  for(int t=0;t<Look;t++){
    int t0 = (t==0)?1:0;
    k_tg<<<g816,b128,0,stream>>>(decb, htR, wtgih, wtghh, c0f, f_bih_tg, f_bhh_tg,
                                 labf, ctf, ctb, htW, t0);
    k_target<<<dim3(Bsz),dim3(64),0,stream>>>(htW, f_reg_w, f_reg_b, outp, labf, t);
    k_dual<<<g816,b128,0,stream>>>(htW, ctb, wtb, wtf);
    k_dual<<<g816,b128,0,stream>>>(htW, ctb, whb, whf);

    for(int l=0;l<Lenc;l++){
      int l0=(l==0)?1:0;
      const u16* hprev = l0 ? midb : (midb + (size_t)(l-1)*BH);
      k_spre<<<g816,b128,0,stream>>>(hprev, ceb, web, wiseq+(size_t)l*BH, wtf, spreb, l0);
      k_sgemm<<<g816,b128,0,stream>>>(spreb, vdb, f_Vd_b, scoref);
      k_softmax<<<dim3(Bsz),dim3(256),0,stream>>>(scoref, f_inp, l, xmodb);
      k_cell<<<g816,b128,0,stream>>>(xmodb, hprev, wspih, wsphh, f_bih_sp, f_bhh_sp,
                                     cef, ceb, midb+(size_t)l*BH, l0);
    }
    for(int l=0;l<Lenc;l++){
      int l0=(l==0)?1:0;
      const u16* hprev = l0 ? mid2b : (mid2b + (size_t)(l-1)*BH);
      k_cell<<<g816,b128,0,stream>>>(midb+(size_t)l*BH, hprev, wmidih, wmidhh,
                                     f_bih_mid, f_bhh_mid, cmidf, (u16*)nullptr,
                                     mid2b+(size_t)l*BH, l0);
    }
    k_scgemm<<<dim3(384,16),b128,0,stream>>>(mid2b, wxb, f_Wx_b, whf, ttb);
    k_scred<<<dim3(Lenc*Bsz),dim3(64),0,stream>>>(ttb, f_V_w, f_V_b, scf);
    k_dec<<<dim3(Bsz),dim3(256),0,stream>>>(scf, mid2b, decb);

    u16* tmp=htR; htR=htW; htW=tmp;
  }
}